// Round 2
// baseline (248.714 us; speedup 1.0000x reference)
//
#include <hip/hip_runtime.h>

// DAG of 1x1 convs, fully fused per-pixel.
// B=64, C=64, H=32, W=32 -> 65536 pixels, per-pixel channel vec of 64.
// states: s0=conv(x0,Wpre0), s1=conv(x1,Wpre1);
// node j (j=2..5): s_j = sum_{s<j} conv(relu(s_s), Wedge[e++])
// out = concat(s2..s5) on channels -> [64, 256, 32, 32]

#define TILE_P 32          // pixels per block
#define RS 68              // padded row stride (floats); 68%32=4 -> weight rows conflict-free
#define TBUF (TILE_P * RS) // 2176 floats = 8704 B per state buffer
#define WBUF (64 * RS)     // 4352 floats = 17408 B weight buffer (64 out-channels!)

// LDS: r0..r3 | xin/r4 (shared: xin dead after k=1, r4 born at k=10) | wb
// total = 5*2176 + 4352 = 15232 floats = 60928 B -> 2 blocks/CU
__global__ __launch_bounds__(256, 2) void dag_kernel(
    const float* __restrict__ x0, const float* __restrict__ x1,
    const float* __restrict__ Wpre, const float* __restrict__ Wedge,
    float* __restrict__ out)
{
    __shared__ __align__(16) float lds[5 * TBUF + WBUF];
    float* rbuf = lds;                 // r0..r3, and r4==buffer 4
    float* xin  = lds + 4 * TBUF;      // aliases r4
    float* wb   = lds + 5 * TBUF;

    const int t  = threadIdx.x;
    const int tp = t & 15;        // pixel group: p in {tp, tp+16}
    const int to = t >> 4;        // 0..15, out-channel group o = 4*to..4*to+3
    const int o0 = to * 4;

    const int blk = blockIdx.x;   // 2048 blocks = 64 b * 32 hw-tiles
    const int b   = blk >> 5;
    const int hw0 = (blk & 31) * TILE_P;

    const float* xg0  = x0 + b * 65536 + hw0;
    const float* xg1  = x1 + b * 65536 + hw0;
    float*       outg = out + b * 262144 + hw0;

    // stage xin <- x0 tile ([p][c] pixel-major, stride RS)
    #pragma unroll
    for (int kk = 0; kk < 8; ++kk) {
        int idx = kk * 256 + t;
        int c = idx >> 5, p = idx & 31;
        xin[p * RS + c] = xg0[c * 1024 + p];
    }

    // prefetch weight matrix 0 into registers
    float wreg[16];
    #pragma unroll
    for (int kk = 0; kk < 16; ++kk) wreg[kk] = Wpre[kk * 256 + t];

    float acc[4][2] = {};

    // conv k: k=0,1 preproc; k=2..15 edges 0..13
    // src 5 == xin (same buffer as 4)
    #pragma unroll
    for (int k = 0; k < 16; ++k) {
        const int src_tab[16] = { 5,5, 0,1, 0,1,2, 0,1,2,3, 0,1,2,3,4 };
        const int dst_tab[16] = { 0,1, -1,2, -1,-1,3, -1,-1,-1,4, -1,-1,-1,-1,-1 };
        const int out_tab[16] = { -1,-1, -1,0, -1,-1,1, -1,-1,-1,2, -1,-1,-1,-1,3 };

        __syncthreads();  // prior iter's wb reads done; prior state/xin writes visible

        // store prefetched weights to LDS ([o][c] stride RS, 64 rows)
        #pragma unroll
        for (int kk = 0; kk < 16; ++kk) {
            int idx = kk * 256 + t;
            wb[(idx >> 6) * RS + (idx & 63)] = wreg[kk];
        }
        // prefetch next conv's weights
        if (k < 15) {
            const float* ws = (k + 1 < 2) ? (Wpre + (k + 1) * 4096)
                                          : (Wedge + (k - 1) * 4096);
            #pragma unroll
            for (int kk = 0; kk < 16; ++kk) wreg[kk] = ws[kk * 256 + t];
        }
        __syncthreads();  // wb ready

        const int si = src_tab[k];
        const float* sp = (si >= 4) ? xin : (rbuf + si * TBUF);

        // acc[i][j] += sum_c wb[o0+i][c] * sp[p_j][c]
        #pragma unroll 4
        for (int c0 = 0; c0 < 64; c0 += 4) {
            float4 wv[4], xv[2];
            #pragma unroll
            for (int i = 0; i < 4; ++i)
                wv[i] = *(const float4*)(wb + (o0 + i) * RS + c0);
            #pragma unroll
            for (int j = 0; j < 2; ++j)
                xv[j] = *(const float4*)(sp + (tp + 16 * j) * RS + c0);
            #pragma unroll
            for (int i = 0; i < 4; ++i) {
                #pragma unroll
                for (int j = 0; j < 2; ++j) {
                    float a = acc[i][j];
                    a = fmaf(wv[i].x, xv[j].x, a);
                    a = fmaf(wv[i].y, xv[j].y, a);
                    a = fmaf(wv[i].z, xv[j].z, a);
                    a = fmaf(wv[i].w, xv[j].w, a);
                    acc[i][j] = a;
                }
            }
        }

        const int ob  = out_tab[k];
        const int dst = dst_tab[k];

        if (ob >= 0) {
            // raw node state -> global output channel block ob
            #pragma unroll
            for (int i = 0; i < 4; ++i) {
                #pragma unroll
                for (int j = 0; j < 2; ++j)
                    outg[(ob * 64 + o0 + i) * 1024 + tp + 16 * j] = acc[i][j];
            }
        }
        if (k == 0) __syncthreads();  // all conv0 xin reads done before restage below
        if (dst >= 0) {
            // relu'd state -> LDS for downstream edges (dst=4 lands in xin buffer)
            float* rd = (dst >= 4) ? xin : (rbuf + dst * TBUF);
            #pragma unroll
            for (int j = 0; j < 2; ++j) {
                float4 v;
                v.x = fmaxf(acc[0][j], 0.f);
                v.y = fmaxf(acc[1][j], 0.f);
                v.z = fmaxf(acc[2][j], 0.f);
                v.w = fmaxf(acc[3][j], 0.f);
                *(float4*)(rd + (tp + 16 * j) * RS + o0) = v;
            }
            #pragma unroll
            for (int i = 0; i < 4; ++i) { acc[i][0] = 0.f; acc[i][1] = 0.f; }
        }
        if (k == 0) {
            // restage xin <- x1 for conv 1 (visible after next top-of-loop sync)
            #pragma unroll
            for (int kk = 0; kk < 8; ++kk) {
                int idx = kk * 256 + t;
                int c = idx >> 5, p = idx & 31;
                xin[p * RS + c] = xg1[c * 1024 + p];
            }
        }
    }
}

extern "C" void kernel_launch(void* const* d_in, const int* in_sizes, int n_in,
                              void* d_out, int out_size, void* d_ws, size_t ws_size,
                              hipStream_t stream) {
    const float* x0    = (const float*)d_in[0];
    const float* x1    = (const float*)d_in[1];
    const float* Wpre  = (const float*)d_in[2];
    const float* Wedge = (const float*)d_in[3];
    float* outp        = (float*)d_out;
    dag_kernel<<<dim3(2048), dim3(256), 0, stream>>>(x0, x1, Wpre, Wedge, outp);
}

// Round 4
// 114.714 us; speedup vs baseline: 2.1681x; 2.1681x over previous
//
#include <hip/hip_runtime.h>

// DAG of 1x1 convs, fully fused, f16 MFMA (fp32 accumulate).
// Per block: 64-pixel tile x 64 channels. 16 convs (2 pre + 14 edges).
// States live in LDS as f16 [p][c], stride 72 f16 (144B rows).
// Wave w: out-ch half mb0=(w&1)*2 (2x16), pixel half nb0=(w>>1)*2 (2x16).
// mfma_f32_16x16x32_f16: A[m=lane&15][k=(lane>>4)*8+j], B[k][n=lane&15],
// D: row(m)=(lane>>4)*4+reg, col(n)=lane&15.  (measured layouts, m89/m120)

typedef _Float16 f16;
typedef _Float16 f16x8 __attribute__((ext_vector_type(8)));
typedef float    f32x4 __attribute__((ext_vector_type(4)));

#define RSH 72            // f16 per row (144B: 16B-aligned, bank-uniform)
#define SB  (64 * RSH)    // 4608 f16 = 9216 B per buffer

__device__ __forceinline__ unsigned int pkrtz(float a, float b) {
    __fp16 h2 __attribute__((ext_vector_type(2))) = __builtin_amdgcn_cvt_pkrtz(a, b);
    return __builtin_bit_cast(unsigned int, h2);
}

__global__ __launch_bounds__(256, 2) void dag_kernel(
    const float* __restrict__ x0, const float* __restrict__ x1,
    const float* __restrict__ Wpre, const float* __restrict__ Wedge,
    float* __restrict__ out)
{
    // buffers 0..4: states (3=xin0/r3, 4=xin1/r4); 5,6: W double buffer
    __shared__ __align__(16) f16 lds[7 * SB];   // 64512 B -> 2 blocks/CU

    const int t    = threadIdx.x;
    const int lane = t & 63;
    const int w    = t >> 6;
    const int pl   = lane & 15;
    const int q    = lane >> 4;
    const int mb0  = (w & 1) * 2;     // out-ch 16-blocks {mb0, mb0+1}
    const int nb0  = (w >> 1) * 2;    // pixel 16-blocks

    const int blk = blockIdx.x;       // 1024 = 64 batches x 16 px-tiles
    const int b   = blk >> 4;
    const int hw0 = (blk & 15) * 64;

    const float* xg[2] = { x0 + b * 65536 + hw0, x1 + b * 65536 + hw0 };
    float* outg = out + b * 262144 + hw0;

    // ---- stage inputs -> f16 [p][c] into buffers 3,4 ----
    {
        const int p  = t & 63;
        const int cg = t >> 6;        // channels cg*16 .. cg*16+15
        #pragma unroll
        for (int inp = 0; inp < 2; ++inp) {
            const float* src = xg[inp] + (cg * 16) * 1024 + p;
            unsigned int u[8];
            #pragma unroll
            for (int i = 0; i < 8; ++i)
                u[i] = pkrtz(src[(2 * i) * 1024], src[(2 * i + 1) * 1024]);
            f16* dst = lds + (3 + inp) * SB + p * RSH + cg * 16;
            ((uint4*)dst)[0] = make_uint4(u[0], u[1], u[2], u[3]);
            ((uint4*)dst)[1] = make_uint4(u[4], u[5], u[6], u[7]);
        }
    }
    // ---- stage W0 -> wb[0] ----
    {
        const int o = t >> 2, cq = t & 3;
        const float4* ws = (const float4*)(Wpre + o * 64 + cq * 16);
        unsigned int u[8];
        #pragma unroll
        for (int i = 0; i < 4; ++i) {
            float4 v = ws[i];
            u[2 * i]     = pkrtz(v.x, v.y);
            u[2 * i + 1] = pkrtz(v.z, v.w);
        }
        f16* dst = lds + 5 * SB + o * RSH + cq * 16;
        ((uint4*)dst)[0] = make_uint4(u[0], u[1], u[2], u[3]);
        ((uint4*)dst)[1] = make_uint4(u[4], u[5], u[6], u[7]);
    }

    f32x4 acc[2][2] = {};

    #pragma unroll
    for (int k = 0; k < 16; ++k) {
        const int src_tab[16] = { 3,4, 0,1, 0,1,2, 0,1,2,3, 0,1,2,3,4 };
        const int dst_tab[16] = { 0,1, -1,2, -1,-1,3, -1,-1,-1,4, -1,-1,-1,-1,-1 };
        const int out_tab[16] = { -1,-1, -1,0, -1,-1,1, -1,-1,-1,2, -1,-1,-1,-1,3 };

        __syncthreads();   // W(k) + state writes from iter k-1 visible;
                           // iter k-1's reads of wb[(k+1)&1] complete.

        // issue global loads of W(k+1) early (latency hidden by MFMAs)
        float4 wr[4];
        if (k < 15) {
            const float* wsrc = ((k + 1 < 2) ? (Wpre + (k + 1) * 4096)
                                             : (Wedge + (k - 1) * 4096))
                                + (t >> 2) * 64 + (t & 3) * 16;
            #pragma unroll
            for (int i = 0; i < 4; ++i) wr[i] = ((const float4*)wsrc)[i];
        }

        // ---- conv k: acc += W * relu-state ----
        const f16* Wl = lds + (5 + (k & 1)) * SB;
        const f16* S  = lds + src_tab[k] * SB;
        #pragma unroll
        for (int kb = 0; kb < 2; ++kb) {
            f16x8 af[2], bf[2];
            #pragma unroll
            for (int i = 0; i < 2; ++i)
                af[i] = *(const f16x8*)(Wl + ((mb0 + i) * 16 + pl) * RSH + kb * 32 + q * 8);
            #pragma unroll
            for (int j = 0; j < 2; ++j)
                bf[j] = *(const f16x8*)(S + ((nb0 + j) * 16 + pl) * RSH + kb * 32 + q * 8);
            #pragma unroll
            for (int i = 0; i < 2; ++i)
                #pragma unroll
                for (int j = 0; j < 2; ++j)
                    acc[i][j] = __builtin_amdgcn_mfma_f32_16x16x32_f16(
                                    af[i], bf[j], acc[i][j], 0, 0, 0);
        }

        // ---- epilogue ----
        if (out_tab[k] >= 0) {   // raw node state -> global
            #pragma unroll
            for (int i = 0; i < 2; ++i)
                #pragma unroll
                for (int j = 0; j < 2; ++j) {
                    const int c = (mb0 + i) * 16 + q * 4;
                    const int p = (nb0 + j) * 16 + pl;
                    #pragma unroll
                    for (int r = 0; r < 4; ++r)
                        outg[(out_tab[k] * 64 + c + r) * 1024 + p] = acc[i][j][r];
                }
        }
        if (dst_tab[k] >= 0) {   // relu'd state -> LDS (f16)
            f16* D = lds + dst_tab[k] * SB;
            #pragma unroll
            for (int i = 0; i < 2; ++i)
                #pragma unroll
                for (int j = 0; j < 2; ++j) {
                    const int c = (mb0 + i) * 16 + q * 4;
                    const int p = (nb0 + j) * 16 + pl;
                    unsigned int u0 = pkrtz(fmaxf(acc[i][j][0], 0.f), fmaxf(acc[i][j][1], 0.f));
                    unsigned int u1 = pkrtz(fmaxf(acc[i][j][2], 0.f), fmaxf(acc[i][j][3], 0.f));
                    *(uint2*)(D + p * RSH + c) = make_uint2(u0, u1);
                }
            #pragma unroll
            for (int i = 0; i < 2; ++i)
                #pragma unroll
                for (int j = 0; j < 2; ++j)
                    acc[i][j] = (f32x4){0.f, 0.f, 0.f, 0.f};
        }

        // ---- store W(k+1) into the other W buffer ----
        if (k < 15) {
            unsigned int u[8];
            #pragma unroll
            for (int i = 0; i < 4; ++i) {
                u[2 * i]     = pkrtz(wr[i].x, wr[i].y);
                u[2 * i + 1] = pkrtz(wr[i].z, wr[i].w);
            }
            f16* dst = lds + (5 + ((k + 1) & 1)) * SB + (t >> 2) * RSH + (t & 3) * 16;
            ((uint4*)dst)[0] = make_uint4(u[0], u[1], u[2], u[3]);
            ((uint4*)dst)[1] = make_uint4(u[4], u[5], u[6], u[7]);
        }
    }
}

extern "C" void kernel_launch(void* const* d_in, const int* in_sizes, int n_in,
                              void* d_out, int out_size, void* d_ws, size_t ws_size,
                              hipStream_t stream) {
    const float* x0    = (const float*)d_in[0];
    const float* x1    = (const float*)d_in[1];
    const float* Wpre  = (const float*)d_in[2];
    const float* Wedge = (const float*)d_in[3];
    float* outp        = (float*)d_out;
    dag_kernel<<<dim3(1024), dim3(256), 0, stream>>>(x0, x1, Wpre, Wedge, outp);
}

// Round 5
// 109.642 us; speedup vs baseline: 2.2684x; 1.0463x over previous
//
#include <hip/hip_runtime.h>

// DAG of 1x1 convs, fully fused, f16 MFMA, ZERO per-conv barriers.
// Wave-private dataflow: each wave owns 16 pixels x all 64 channels, so every
// state it reads was written by itself -> in-wave LDS ordering suffices.
// Weights: pre-kernel converts W (f32) -> f16 A-fragment layout in d_ws;
// main kernel loads W fragments global->VGPR, double-buffered one conv ahead.
// mfma_f32_16x16x32_f16: A[m=lane&15][k=(lane>>4)*8+j], B[n=lane&15][k=...],
// D: row m=(lane>>4)*4+reg, col n=lane&15. (verified by R4 absmax 0.0625)

typedef _Float16 f16;
typedef _Float16 f16x8 __attribute__((ext_vector_type(8)));
typedef float    f32x4 __attribute__((ext_vector_type(4)));

#define RSH 72            // f16 per state row (144B: 16B-aligned, 2-way banks)
#define SB  (64 * RSH)    // 4608 f16 = 9216 B per state buffer

__device__ __forceinline__ unsigned int pkrtz(float a, float b) {
    __fp16 h2 __attribute__((ext_vector_type(2))) = __builtin_amdgcn_cvt_pkrtz(a, b);
    return __builtin_bit_cast(unsigned int, h2);
}

// ---- kernel 1: W f32 [16][64][64] -> f16 A-fragment layout in ws ----
// flat u = ((k*2+kb)*4+q)*64 + row; ws[u*8 .. +7] = W[k][row][kb*32+q*8 .. +7]
// main-kernel lane (pl,q) then loads frag(k,kb,i) at
//   ws + (k*2+kb)*2048 + q*512 + (i*16+pl)*8   (f16 elements) -- coalesced.
__global__ __launch_bounds__(256) void wconv_kernel(
    const float* __restrict__ Wpre, const float* __restrict__ Wedge,
    f16* __restrict__ ws)
{
    const int u   = blockIdx.x * 256 + threadIdx.x;  // 0..8191
    const int k   = u >> 9;
    const int rem = u & 511;
    const int g   = rem >> 6;        // kb*4+q
    const int row = rem & 63;
    const float* src = ((k < 2) ? (Wpre + k * 4096) : (Wedge + (k - 2) * 4096))
                       + row * 64 + (g >> 2) * 32 + (g & 3) * 8;
    float4 v0 = ((const float4*)src)[0];
    float4 v1 = ((const float4*)src)[1];
    ((uint4*)ws)[u] = make_uint4(pkrtz(v0.x, v0.y), pkrtz(v0.z, v0.w),
                                 pkrtz(v1.x, v1.y), pkrtz(v1.z, v1.w));
}

// ---- kernel 2: the fused DAG ----
__global__ __launch_bounds__(256, 3) void dag_kernel(
    const float* __restrict__ x0, const float* __restrict__ x1,
    const f16* __restrict__ wf, float* __restrict__ out)
{
    // 5 state buffers [p][c] f16 (0..2: r0..r2; 3: xin0/r3; 4: xin1/r4)
    __shared__ __align__(16) f16 lds[5 * SB];   // 46080 B -> 3 blocks/CU

    const int t    = threadIdx.x;
    const int lane = t & 63;
    const int wv   = t >> 6;       // wave owns pixels wv*16 .. wv*16+15
    const int pl   = lane & 15;
    const int q    = lane >> 4;

    const int blk = blockIdx.x;    // 1024 = 64 batches x 16 px-tiles
    const int b   = blk >> 4;
    const int hw0 = (blk & 15) * 64;

    const float* xg[2] = { x0 + b * 65536 + hw0, x1 + b * 65536 + hw0 };
    float* outg = out + b * 262144 + hw0;

    // lane-specific W fragment base; frag(k,kb,i) at + (k*2+kb)*2048 + i*128
    const f16* wl = wf + q * 512 + pl * 8;

    // load W(0) fragments (overlaps input staging)
    f16x8 wA[2][2][4];    // [parity][kb][m-tile]
    #pragma unroll
    for (int kb = 0; kb < 2; ++kb)
        #pragma unroll
        for (int i = 0; i < 4; ++i)
            wA[0][kb][i] = *(const f16x8*)(wl + kb * 2048 + i * 128);

    // ---- cooperative input staging -> f16 [p][c] buffers 3,4 ----
    {
        const int p = t & 63, cg = t >> 6;   // channels cg*16 .. +15
        #pragma unroll
        for (int inp = 0; inp < 2; ++inp) {
            const float* src = xg[inp] + (cg * 16) * 1024 + p;
            unsigned int u[8];
            #pragma unroll
            for (int i = 0; i < 8; ++i)
                u[i] = pkrtz(src[(2 * i) * 1024], src[(2 * i + 1) * 1024]);
            f16* dst = lds + (3 + inp) * SB + p * RSH + cg * 16;
            ((uint4*)dst)[0] = make_uint4(u[0], u[1], u[2], u[3]);
            ((uint4*)dst)[1] = make_uint4(u[4], u[5], u[6], u[7]);
        }
    }
    __syncthreads();   // the ONLY barrier: staging visible to all waves

    f32x4 acc[4] = {};   // 4 m-tiles: all 64 out-ch for this wave's 16 px

    #pragma unroll
    for (int k = 0; k < 16; ++k) {
        const int src_tab[16] = { 3,4, 0,1, 0,1,2, 0,1,2,3, 0,1,2,3,4 };
        const int dst_tab[16] = { 0,1, -1,2, -1,-1,3, -1,-1,-1,4, -1,-1,-1,-1,-1 };
        const int out_tab[16] = { -1,-1, -1,0, -1,-1,1, -1,-1,-1,2, -1,-1,-1,-1,3 };
        const int cur = k & 1, nxt = cur ^ 1;

        // prefetch W(k+1) fragments (latency hidden by this conv's MFMAs)
        if (k < 15) {
            const f16* wn = wl + (k + 1) * 4096;
            #pragma unroll
            for (int kb = 0; kb < 2; ++kb)
                #pragma unroll
                for (int i = 0; i < 4; ++i)
                    wA[nxt][kb][i] = *(const f16x8*)(wn + kb * 2048 + i * 128);
        }

        // B fragments from this wave's own state rows
        const f16* S = lds + src_tab[k] * SB + (wv * 16 + pl) * RSH;
        f16x8 bf[2];
        #pragma unroll
        for (int kb = 0; kb < 2; ++kb)
            bf[kb] = *(const f16x8*)(S + kb * 32 + q * 8);

        #pragma unroll
        for (int kb = 0; kb < 2; ++kb)
            #pragma unroll
            for (int i = 0; i < 4; ++i)
                acc[i] = __builtin_amdgcn_mfma_f32_16x16x32_f16(
                             wA[cur][kb][i], bf[kb], acc[i], 0, 0, 0);

        if (out_tab[k] >= 0) {   // raw node state -> global
            const int p = wv * 16 + pl;
            #pragma unroll
            for (int i = 0; i < 4; ++i) {
                const int c = i * 16 + q * 4;
                #pragma unroll
                for (int r = 0; r < 4; ++r)
                    outg[(out_tab[k] * 64 + c + r) * 1024 + p] = acc[i][r];
            }
        }
        if (dst_tab[k] >= 0) {   // relu'd state -> own LDS rows (in-wave order)
            f16* D = lds + dst_tab[k] * SB + (wv * 16 + pl) * RSH;
            #pragma unroll
            for (int i = 0; i < 4; ++i) {
                unsigned int u0 = pkrtz(fmaxf(acc[i][0], 0.f), fmaxf(acc[i][1], 0.f));
                unsigned int u1 = pkrtz(fmaxf(acc[i][2], 0.f), fmaxf(acc[i][3], 0.f));
                *(uint2*)(D + i * 16 + q * 4) = make_uint2(u0, u1);
            }
            #pragma unroll
            for (int i = 0; i < 4; ++i) acc[i] = (f32x4){0.f, 0.f, 0.f, 0.f};
        }
    }
}

extern "C" void kernel_launch(void* const* d_in, const int* in_sizes, int n_in,
                              void* d_out, int out_size, void* d_ws, size_t ws_size,
                              hipStream_t stream) {
    const float* x0    = (const float*)d_in[0];
    const float* x1    = (const float*)d_in[1];
    const float* Wpre  = (const float*)d_in[2];
    const float* Wedge = (const float*)d_in[3];
    float* outp        = (float*)d_out;
    f16*   wfrag       = (f16*)d_ws;          // 131072 B used

    wconv_kernel<<<dim3(32), dim3(256), 0, stream>>>(Wpre, Wedge, wfrag);
    dag_kernel<<<dim3(1024), dim3(256), 0, stream>>>(x0, x1, wfrag, outp);
}

// Round 6
// 102.458 us; speedup vs baseline: 2.4275x; 1.0701x over previous
//
#include <hip/hip_runtime.h>

// DAG of 1x1 convs, fully fused, f16 MFMA, zero per-conv barriers.
// R6: 32 px/wave (2-wave blocks) halves redundant W L2 traffic; 4 LDS state
// buffers (dual-accumulator edge reordering) -> 36 KB -> 4 blocks/CU, no tail.
// Each wave owns 32 pixels x all 64 channels; all state reuse is wave-private.
// Schedule (conv index k -> weight widx / src buf / acc / retire):
//  k  : 0  1  2  3  4  5  6  7  8  9 10 11 12 13 14 15
//  w  : 0  1  2  3  4  5  6  7 11  8 12  9 13 14 10 15   (0,1=pre; 2+e=edge e)
//  src: 2  3  0  1  0  1  2  0  0  1  1  2  2  3  3  0
//  acc: A  A  A  A  A  A  A  A  B  A  B  A  B  B  A  B
//  ret: s0 s1 -  n2 -  -  n3 -  -  -  -  -  -  -  n4 n5
// buffers: s0->0, s1->1, s2->2 (was xin0), s3->3 (was xin1), s4->0 (s0 dead)

typedef _Float16 f16;
typedef _Float16 f16x8 __attribute__((ext_vector_type(8)));
typedef float    f32x4 __attribute__((ext_vector_type(4)));

#define RSH 72            // f16 per state row (144B: 16B-aligned, 2-way banks)
#define SB  (64 * RSH)    // 4608 f16 = 9216 B per state buffer

__device__ __forceinline__ unsigned int pkrtz(float a, float b) {
    __fp16 h2 __attribute__((ext_vector_type(2))) = __builtin_amdgcn_cvt_pkrtz(a, b);
    return __builtin_bit_cast(unsigned int, h2);
}

// ---- kernel 1: W f32 [16][64][64] -> f16 A-fragment layout in ws ----
// flat u = ((k*2+kb)*4+q)*64 + row; ws[u*8 .. +7] = W[k][row][kb*32+q*8 .. +7]
__global__ __launch_bounds__(256) void wconv_kernel(
    const float* __restrict__ Wpre, const float* __restrict__ Wedge,
    f16* __restrict__ ws)
{
    const int u   = blockIdx.x * 256 + threadIdx.x;  // 0..8191
    const int k   = u >> 9;
    const int rem = u & 511;
    const int g   = rem >> 6;        // kb*4+q
    const int row = rem & 63;
    const float* src = ((k < 2) ? (Wpre + k * 4096) : (Wedge + (k - 2) * 4096))
                       + row * 64 + (g >> 2) * 32 + (g & 3) * 8;
    float4 v0 = ((const float4*)src)[0];
    float4 v1 = ((const float4*)src)[1];
    ((uint4*)ws)[u] = make_uint4(pkrtz(v0.x, v0.y), pkrtz(v0.z, v0.w),
                                 pkrtz(v1.x, v1.y), pkrtz(v1.z, v1.w));
}

// ---- kernel 2: the fused DAG ----
__global__ __launch_bounds__(128, 2) void dag_kernel(
    const float* __restrict__ x0, const float* __restrict__ x1,
    const f16* __restrict__ wf, float* __restrict__ out)
{
    __shared__ __align__(16) f16 lds[4 * SB];   // 36864 B -> 4 blocks/CU

    const int t    = threadIdx.x;   // 128 threads = 2 waves
    const int lane = t & 63;
    const int wv   = t >> 6;        // wave owns pixels wv*32 .. wv*32+31
    const int pl   = lane & 15;
    const int q    = lane >> 4;

    const int blk = blockIdx.x;     // 1024 = 64 batches x 16 px-tiles (4/CU, no tail)
    const int b   = blk >> 4;
    const int hw0 = (blk & 15) * 64;

    const float* xg[2] = { x0 + b * 65536 + hw0, x1 + b * 65536 + hw0 };
    float* outg = out + b * 262144 + hw0;

    // lane-specific W fragment base; frag(widx,kb,i) at + (widx*2+kb)*2048 + i*128
    const f16* wl = wf + q * 512 + pl * 8;

    f16x8 wA[2][2][4];    // [parity][kb][m-tile], double-buffered one conv ahead
    #pragma unroll
    for (int kb = 0; kb < 2; ++kb)
        #pragma unroll
        for (int i = 0; i < 4; ++i)
            wA[0][kb][i] = *(const f16x8*)(wl + kb * 2048 + i * 128);

    // ---- cooperative input staging -> f16 [p][c] buffers 2 (x0), 3 (x1) ----
    {
        const int p = t & 63, h = t >> 6;       // h: channel half (32 ch)
        #pragma unroll
        for (int inp = 0; inp < 2; ++inp) {
            const float* src = xg[inp] + (h * 32) * 1024 + p;
            unsigned int u[16];
            #pragma unroll
            for (int i = 0; i < 16; ++i)
                u[i] = pkrtz(src[(2 * i) * 1024], src[(2 * i + 1) * 1024]);
            uint4* dst = (uint4*)(lds + (2 + inp) * SB + p * RSH + h * 32);
            dst[0] = make_uint4(u[0],  u[1],  u[2],  u[3]);
            dst[1] = make_uint4(u[4],  u[5],  u[6],  u[7]);
            dst[2] = make_uint4(u[8],  u[9],  u[10], u[11]);
            dst[3] = make_uint4(u[12], u[13], u[14], u[15]);
        }
    }
    __syncthreads();   // the ONLY barrier

    f32x4 accA[2][4] = {};   // [j-tile][m-tile]
    f32x4 accB[2][4] = {};

    const int widx_tab[16] = {0,1, 2,3, 4,5,6, 7,11, 8,12, 9,13, 14, 10, 15};
    const int src_tab [16] = {2,3, 0,1, 0,1,2, 0,0,  1,1,  2,2,  3,  3,  0};
    const int asel_tab[16] = {0,0, 0,0, 0,0,0, 0,1,  0,1,  0,1,  1,  0,  1};
    const int out_tab [16] = {-1,-1, -1,0, -1,-1,1, -1,-1, -1,-1, -1,-1, -1, 2, 3};
    const int dst_tab [16] = { 0, 1, -1,2, -1,-1,3, -1,-1, -1,-1, -1,-1, -1, 0,-1};

    #pragma unroll
    for (int k = 0; k < 16; ++k) {
        const int cur = k & 1, nxt = cur ^ 1;

        // prefetch W(k+1) fragments (L2-resident; latency hidden by 16 MFMAs)
        if (k < 15) {
            const f16* wn = wl + widx_tab[k + 1] * 4096;
            #pragma unroll
            for (int kb = 0; kb < 2; ++kb)
                #pragma unroll
                for (int i = 0; i < 4; ++i)
                    wA[nxt][kb][i] = *(const f16x8*)(wn + kb * 2048 + i * 128);
        }

        // B fragments from this wave's own 32 state rows
        const f16* S = lds + src_tab[k] * SB;
        f16x8 bf[2][2];
        #pragma unroll
        for (int jj = 0; jj < 2; ++jj)
            #pragma unroll
            for (int kb = 0; kb < 2; ++kb)
                bf[jj][kb] = *(const f16x8*)(S + (wv * 32 + jj * 16 + pl) * RSH
                                               + kb * 32 + q * 8);

        auto step = [&](f32x4 (&acc)[2][4]) {
            #pragma unroll
            for (int jj = 0; jj < 2; ++jj)
                #pragma unroll
                for (int kb = 0; kb < 2; ++kb)
                    #pragma unroll
                    for (int i = 0; i < 4; ++i)
                        acc[jj][i] = __builtin_amdgcn_mfma_f32_16x16x32_f16(
                                         wA[cur][kb][i], bf[jj][kb], acc[jj][i], 0, 0, 0);
        };
        auto retire = [&](f32x4 (&acc)[2][4]) {
            if (out_tab[k] >= 0) {   // raw node state -> global
                #pragma unroll
                for (int jj = 0; jj < 2; ++jj) {
                    const int p = wv * 32 + jj * 16 + pl;
                    #pragma unroll
                    for (int i = 0; i < 4; ++i) {
                        const int c = i * 16 + q * 4;
                        #pragma unroll
                        for (int r = 0; r < 4; ++r)
                            outg[(out_tab[k] * 64 + c + r) * 1024 + p] = acc[jj][i][r];
                    }
                }
            }
            if (dst_tab[k] >= 0) {   // relu'd state -> own LDS rows
                f16* D = lds + dst_tab[k] * SB;
                #pragma unroll
                for (int jj = 0; jj < 2; ++jj) {
                    f16* Dp = D + (wv * 32 + jj * 16 + pl) * RSH;
                    #pragma unroll
                    for (int i = 0; i < 4; ++i) {
                        unsigned int u0 = pkrtz(fmaxf(acc[jj][i][0], 0.f),
                                                fmaxf(acc[jj][i][1], 0.f));
                        unsigned int u1 = pkrtz(fmaxf(acc[jj][i][2], 0.f),
                                                fmaxf(acc[jj][i][3], 0.f));
                        *(uint2*)(Dp + i * 16 + q * 4) = make_uint2(u0, u1);
                    }
                }
            }
            if (out_tab[k] >= 0 || dst_tab[k] >= 0) {
                #pragma unroll
                for (int jj = 0; jj < 2; ++jj)
                    #pragma unroll
                    for (int i = 0; i < 4; ++i)
                        acc[jj][i] = (f32x4){0.f, 0.f, 0.f, 0.f};
            }
        };

        if (asel_tab[k] == 0) { step(accA); retire(accA); }
        else                  { step(accB); retire(accB); }
    }
}

extern "C" void kernel_launch(void* const* d_in, const int* in_sizes, int n_in,
                              void* d_out, int out_size, void* d_ws, size_t ws_size,
                              hipStream_t stream) {
    const float* x0    = (const float*)d_in[0];
    const float* x1    = (const float*)d_in[1];
    const float* Wpre  = (const float*)d_in[2];
    const float* Wedge = (const float*)d_in[3];
    float* outp        = (float*)d_out;
    f16*   wfrag       = (f16*)d_ws;          // 131072 B used

    wconv_kernel<<<dim3(32), dim3(256), 0, stream>>>(Wpre, Wedge, wfrag);
    dag_kernel<<<dim3(1024), dim3(128), 0, stream>>>(x0, x1, wfrag, outp);
}